// Round 11
// baseline (71.637 us; speedup 1.0000x reference)
//
#include <hip/hip_runtime.h>
#include <hip/hip_bf16.h>
#include <math.h>

#define B_ 4
#define S_ 2048
#define D_ 256
#define H_ 8

typedef __attribute__((ext_vector_type(8))) __bf16 bf16x8;
typedef __attribute__((ext_vector_type(4))) float f32x4;

__device__ inline ushort f2bf(float x) {
  unsigned u = __builtin_bit_cast(unsigned, x);
  unsigned r = u + 0x7fffu + ((u >> 16) & 1u);
  return (ushort)(r >> 16);
}

__device__ inline unsigned cvtpk(float lo, float hi) {
  unsigned r;
  asm("v_cvt_pk_bf16_f32 %0, %1, %2" : "=v"(r) : "v"(lo), "v"(hi));
  return r;
}

__device__ inline bf16x8 load8(const ushort* p) {
  return __builtin_bit_cast(bf16x8, *(const uint4*)p);
}

// ---- prepass: f32 -> bf16 (pos) ----
__global__ void cvt_bf16_kernel(const float* __restrict__ in, ushort* __restrict__ out, int n4) {
  int i = blockIdx.x * blockDim.x + threadIdx.x;
  if (i >= n4) return;
  float4 v = ((const float4*)in)[i];
  ushort4 o;
  o.x = f2bf(v.x); o.y = f2bf(v.y); o.z = f2bf(v.z); o.w = f2bf(v.w);
  ((ushort4*)out)[i] = o;
}

// ---- prepass: Vt[bh][d][s], mask folded in, key-permuted columns per 32-tile ----
__global__ void build_vt_kernel(const float* __restrict__ x, const float* __restrict__ mask,
                                ushort* __restrict__ vt) {
  __shared__ ushort tile[32][33];
  int s0 = blockIdx.x * 32;
  int bh = blockIdx.y;
  int b = bh >> 3, h = bh & 7;
  int tx = threadIdx.x, ty = threadIdx.y;
  float mval = mask[b * S_ + s0 + ty];
  tile[ty][tx] = f2bf(x[((size_t)(b * S_ + s0 + ty)) * D_ + h * 32 + tx] * mval);
  __syncthreads();
  int kx = ((tx >> 1) & 12) + (tx & 3) + ((tx & 4) << 2);  // kappa(tx)
  vt[((size_t)bh * 32 + ty) * S_ + s0 + tx] = tile[kx][ty];
}

// ---- prepass: kappa-permuted bf16 mask ----
__global__ void build_maskp_kernel(const float* __restrict__ mask, ushort* __restrict__ maskp, int n) {
  int i = blockIdx.x * blockDim.x + threadIdx.x;
  if (i >= n) return;
  int t = i & 31;
  int kx = ((t >> 1) & 12) + (t & 3) + ((t & 4) << 2);
  maskp[i] = f2bf(mask[(i & ~31) + kx]);
}

// ---- prepass: Wt[n][k] = W[k][n] as bf16 ----
__global__ void build_wt_kernel(const float* __restrict__ w, ushort* __restrict__ wt) {
  __shared__ ushort tile[32][33];
  int k0 = blockIdx.x * 32;
  int n0 = blockIdx.y * 32;
  int tx = threadIdx.x, ty = threadIdx.y;
  tile[ty][tx] = f2bf(w[(k0 + ty) * D_ + n0 + tx]);
  __syncthreads();
  wt[(n0 + ty) * D_ + k0 + tx] = tile[tx][ty];
}

// ---- flash attention v4: block = 4 waves x 64q (256 q), shared K/V tile via LDS,
//      double-buffered, 1 barrier/tile; each wave does the full 2048-key range ----
__global__ __launch_bounds__(256) void attn_kernel(
    const ushort* __restrict__ posbf,
    const ushort* __restrict__ vt,
    const ushort* __restrict__ maskp,
    ushort* __restrict__ attnbf) {
  // [buf][kv][chunk][row][8] : kv=0 K tile ([dimchunk][key][8dims]),
  //                            kv=1 V tile ([keychunk][d][8keys])
  __shared__ __align__(16) ushort sbuf[2][2][4][32][8];  // 8 KB

  const int tid = threadIdx.x;
  const int wid = tid >> 6, lane = tid & 63;
  const int c = lane & 15, g = lane >> 4;
  const int blk = blockIdx.x;
  const int bh = blk & 31;   // XCD co-location: blk%8 = bh%8
  const int qb = blk >> 5;   // 0..7
  const int b = bh >> 3, h = bh & 7;
  const int q0 = qb * 256 + wid * 64;

  const ushort* posb = posbf + (size_t)b * S_ * D_;
  const ushort* vtb = vt + (size_t)bh * 32 * S_;
  const ushort* mb = maskp + (size_t)b * S_ + g * 8;

  // 4 Q fragments (B' operand): chunk j covers queries q0+16j+c
  bf16x8 fq[4];
#pragma unroll
  for (int j = 0; j < 4; ++j)
    fq[j] = load8(posb + (size_t)(q0 + 16 * j + c) * D_ + h * 32 + g * 8);

  // staging assignment: waves 0,1 stage K (chunks sg = dims), waves 2,3 stage V (sg = keychunk)
  const int kv = wid >> 1;                  // 0=K, 1=V
  const int sl = lane & 31;                 // key (K) or d (V)
  const int sg = (lane >> 5) + (wid & 1) * 2;  // chunk 0..3
  const ushort* ssrc = (kv == 0)
      ? (posb + (size_t)sl * D_ + h * 32 + sg * 8)   // K[key=sl][dims h*32+sg*8..+8]
      : (vtb + (size_t)sl * S_ + sg * 8);            // Vt[d=sl][keys sg*8..+8]
  const size_t sstep = (kv == 0) ? (size_t)(32 * D_) : (size_t)32;

  const f32x4 zero = {0.f, 0.f, 0.f, 0.f};
  f32x4 o0[4], o1[4], o2[4];
#pragma unroll
  for (int j = 0; j < 4; ++j) { o0[j] = zero; o1[j] = zero; o2[j] = zero; }

  const float C1 = 0.42044820762685725f * 1.44269504088896340f; // RS * log2e
  const float C2 = -16.0f * 1.44269504088896340f;               // -OFF * log2e

  // prologue: stage tile 0 into buf 0
  {
    bf16x8 st = load8(ssrc);
    *(uint4*)(&sbuf[0][kv][sg][sl][0]) = __builtin_bit_cast(uint4, st);
  }
  bf16x8 am = load8(mb);
  __syncthreads();

  int cur = 0;
  for (int t = 0; t < 64; ++t) {
    int tn = (t + 1) & 63;  // wraps; final stage unused
    bf16x8 nst = load8(ssrc + (size_t)tn * sstep);
    bf16x8 nm = load8(mb + tn * 32);

    // fragments from LDS (2-way bank aliasing only)
    bf16x8 ak0 = load8(&sbuf[cur][0][g][c][0]);
    bf16x8 ak1 = load8(&sbuf[cur][0][g][16 + c][0]);
    bf16x8 av0 = load8(&sbuf[cur][1][g][c][0]);
    bf16x8 av1 = load8(&sbuf[cur][1][g][16 + c][0]);

#pragma unroll
    for (int j = 0; j < 4; ++j) {
      f32x4 s0 = __builtin_amdgcn_mfma_f32_16x16x32_bf16(ak0, fq[j], zero, 0, 0, 0);
      f32x4 s1 = __builtin_amdgcn_mfma_f32_16x16x32_bf16(ak1, fq[j], zero, 0, 0, 0);

      float p0 = __builtin_amdgcn_exp2f(fmaf(s0[0], C1, C2));
      float p1 = __builtin_amdgcn_exp2f(fmaf(s0[1], C1, C2));
      float p2 = __builtin_amdgcn_exp2f(fmaf(s0[2], C1, C2));
      float p3 = __builtin_amdgcn_exp2f(fmaf(s0[3], C1, C2));
      float p4 = __builtin_amdgcn_exp2f(fmaf(s1[0], C1, C2));
      float p5 = __builtin_amdgcn_exp2f(fmaf(s1[1], C1, C2));
      float p6 = __builtin_amdgcn_exp2f(fmaf(s1[2], C1, C2));
      float p7 = __builtin_amdgcn_exp2f(fmaf(s1[3], C1, C2));

      uint4 uw = make_uint4(cvtpk(p0, p1), cvtpk(p2, p3), cvtpk(p4, p5), cvtpk(p6, p7));
      bf16x8 fp = __builtin_bit_cast(bf16x8, uw);

      o0[j] = __builtin_amdgcn_mfma_f32_16x16x32_bf16(fp, av0, o0[j], 0, 0, 0);
      o1[j] = __builtin_amdgcn_mfma_f32_16x16x32_bf16(fp, av1, o1[j], 0, 0, 0);
      o2[j] = __builtin_amdgcn_mfma_f32_16x16x32_bf16(fp, am, o2[j], 0, 0, 0);
    }

    // write next tile into the other buffer, then one barrier
    *(uint4*)(&sbuf[cur ^ 1][kv][sg][sl][0]) = __builtin_bit_cast(uint4, nst);
    __syncthreads();
    cur ^= 1;
    am = nm;
  }

  // epilogue: each wave owns its 64 q rows completely; o2[j][r] = lsum (same across c)
  ushort* ob = attnbf + (size_t)(b * S_ + q0) * D_ + h * 32;
#pragma unroll
  for (int j = 0; j < 4; ++j) {
#pragma unroll
    for (int r = 0; r < 4; ++r) {
      float ir = 1.f / o2[j][r];
      int row = 16 * j + 4 * g + r;
      ob[(size_t)row * D_ + c] = f2bf(o0[j][r] * ir);
      ob[(size_t)row * D_ + 16 + c] = f2bf(o1[j][r] * ir);
    }
  }
}

// ---- projection GEMM: out = relu(attn @ W + b) ----
__global__ __launch_bounds__(256) void proj_kernel(
    const ushort* __restrict__ attnbf,
    const ushort* __restrict__ wt,
    const float* __restrict__ bias,
    float* __restrict__ out) {
  const int tid = threadIdx.x;
  const int wid = tid >> 6, lane = tid & 63;
  const int c = lane & 15, g = lane >> 4;
  const int m0 = blockIdx.x * 64 + wid * 16;
  const int n0 = blockIdx.y * 64;

  f32x4 acc[4];
#pragma unroll
  for (int nb = 0; nb < 4; ++nb) acc[nb] = (f32x4){0.f, 0.f, 0.f, 0.f};

  for (int k0 = 0; k0 < D_; k0 += 32) {
    bf16x8 fa = load8(attnbf + (size_t)(m0 + c) * D_ + k0 + 8 * g);
#pragma unroll
    for (int nb = 0; nb < 4; ++nb) {
      bf16x8 fb = load8(wt + (size_t)(n0 + nb * 16 + c) * D_ + k0 + 8 * g);
      acc[nb] = __builtin_amdgcn_mfma_f32_16x16x32_bf16(fa, fb, acc[nb], 0, 0, 0);
    }
  }

#pragma unroll
  for (int nb = 0; nb < 4; ++nb) {
    int n = n0 + nb * 16 + c;
    float bv = bias[n];
#pragma unroll
    for (int r = 0; r < 4; ++r) {
      int mrow = m0 + 4 * g + r;
      float v = acc[nb][r] + bv;
      out[(size_t)mrow * D_ + n] = fmaxf(v, 0.f);
    }
  }
}

extern "C" void kernel_launch(void* const* d_in, const int* in_sizes, int n_in,
                              void* d_out, int out_size, void* d_ws, size_t ws_size,
                              hipStream_t stream) {
  const float* x = (const float*)d_in[0];     // [B,S,D]
  const float* mask = (const float*)d_in[1];  // [B,S,1]
  const float* pos = (const float*)d_in[2];   // [B,S,D]
  const float* W = (const float*)d_in[3];     // [D,D]
  const float* bias = (const float*)d_in[4];  // [D]
  float* out = (float*)d_out;

  const size_t NE = (size_t)B_ * S_ * D_;  // 2097152
  ushort* posbf = (ushort*)d_ws;
  ushort* vtbuf = posbf + NE;
  ushort* attnbf = vtbuf + NE;
  ushort* wtbuf = attnbf + NE;                 // D*D = 65536
  ushort* maskpbuf = wtbuf + (size_t)D_ * D_;  // B*S = 8192

  cvt_bf16_kernel<<<(int)(NE / 4 / 256), 256, 0, stream>>>(pos, posbf, (int)(NE / 4));
  build_vt_kernel<<<dim3(S_ / 32, B_ * H_), dim3(32, 32), 0, stream>>>(x, mask, vtbuf);
  build_maskp_kernel<<<(B_ * S_) / 256, 256, 0, stream>>>(mask, maskpbuf, B_ * S_);
  build_wt_kernel<<<dim3(D_ / 32, D_ / 32), dim3(32, 32), 0, stream>>>(W, wtbuf);
  attn_kernel<<<256, 256, 0, stream>>>(posbf, vtbuf, maskpbuf, attnbf);
  proj_kernel<<<dim3((B_ * S_) / 64, D_ / 64), 256, 0, stream>>>(attnbf, wtbuf, bias, out);
}

// Round 12
// 70.866 us; speedup vs baseline: 1.0109x; 1.0109x over previous
//
#include <hip/hip_runtime.h>
#include <hip/hip_bf16.h>
#include <math.h>

#define B_ 4
#define S_ 2048
#define D_ 256
#define H_ 8

typedef __attribute__((ext_vector_type(8))) __bf16 bf16x8;
typedef __attribute__((ext_vector_type(4))) float f32x4;

__device__ inline ushort f2bf(float x) {
  unsigned u = __builtin_bit_cast(unsigned, x);
  unsigned r = u + 0x7fffu + ((u >> 16) & 1u);
  return (ushort)(r >> 16);
}

__device__ inline unsigned cvtpk(float lo, float hi) {
  unsigned r;
  asm("v_cvt_pk_bf16_f32 %0, %1, %2" : "=v"(r) : "v"(lo), "v"(hi));
  return r;
}

__device__ inline bf16x8 load8(const ushort* p) {
  return __builtin_bit_cast(bf16x8, *(const uint4*)p);
}

// ---- prepass: f32 -> bf16 (pos) ----
__global__ void cvt_bf16_kernel(const float* __restrict__ in, ushort* __restrict__ out, int n4) {
  int i = blockIdx.x * blockDim.x + threadIdx.x;
  if (i >= n4) return;
  float4 v = ((const float4*)in)[i];
  ushort4 o;
  o.x = f2bf(v.x); o.y = f2bf(v.y); o.z = f2bf(v.z); o.w = f2bf(v.w);
  ((ushort4*)out)[i] = o;
}

// ---- prepass: Vt[bh][d][s], mask folded in, key-permuted columns per 32-tile ----
__global__ void build_vt_kernel(const float* __restrict__ x, const float* __restrict__ mask,
                                ushort* __restrict__ vt) {
  __shared__ ushort tile[32][33];
  int s0 = blockIdx.x * 32;
  int bh = blockIdx.y;
  int b = bh >> 3, h = bh & 7;
  int tx = threadIdx.x, ty = threadIdx.y;
  float mval = mask[b * S_ + s0 + ty];
  tile[ty][tx] = f2bf(x[((size_t)(b * S_ + s0 + ty)) * D_ + h * 32 + tx] * mval);
  __syncthreads();
  int kx = ((tx >> 1) & 12) + (tx & 3) + ((tx & 4) << 2);  // kappa(tx)
  vt[((size_t)bh * 32 + ty) * S_ + s0 + tx] = tile[kx][ty];
}

// ---- prepass: kappa-permuted bf16 mask ----
__global__ void build_maskp_kernel(const float* __restrict__ mask, ushort* __restrict__ maskp, int n) {
  int i = blockIdx.x * blockDim.x + threadIdx.x;
  if (i >= n) return;
  int t = i & 31;
  int kx = ((t >> 1) & 12) + (t & 3) + ((t & 4) << 2);
  maskp[i] = f2bf(mask[(i & ~31) + kx]);
}

// ---- prepass: Wt[n][k] = W[k][n] as bf16 ----
__global__ void build_wt_kernel(const float* __restrict__ w, ushort* __restrict__ wt) {
  __shared__ ushort tile[32][33];
  int k0 = blockIdx.x * 32;
  int n0 = blockIdx.y * 32;
  int tx = threadIdx.x, ty = threadIdx.y;
  tile[ty][tx] = f2bf(w[(k0 + ty) * D_ + n0 + tx]);
  __syncthreads();
  wt[(n0 + ty) * D_ + k0 + tx] = tile[tx][ty];
}

// ---- flash attention v5: block = 4 waves x 32q (128 q), shared K/V tile via LDS,
//      double-buffered, 512 blocks -> 2 blocks/CU -> 2 waves/SIMD ----
__global__ __launch_bounds__(256) void attn_kernel(
    const ushort* __restrict__ posbf,
    const ushort* __restrict__ vt,
    const ushort* __restrict__ maskp,
    ushort* __restrict__ attnbf) {
  // [buf][kv][chunk][row][8] : kv=0 K tile ([dimchunk][key][8dims]),
  //                            kv=1 V tile ([keychunk][d][8keys])
  __shared__ __align__(16) ushort sbuf[2][2][4][32][8];  // 8 KB

  const int tid = threadIdx.x;
  const int wid = tid >> 6, lane = tid & 63;
  const int c = lane & 15, g = lane >> 4;
  const int blk = blockIdx.x;
  const int bh = blk & 31;   // XCD co-location: blk%8 = bh%8
  const int qb = blk >> 5;   // 0..15
  const int b = bh >> 3, h = bh & 7;
  const int q0 = qb * 128 + wid * 32;

  const ushort* posb = posbf + (size_t)b * S_ * D_;
  const ushort* vtb = vt + (size_t)bh * 32 * S_;
  const ushort* mb = maskp + (size_t)b * S_ + g * 8;

  // 2 Q fragments (B' operand): chunk j covers queries q0+16j+c
  bf16x8 fq[2];
#pragma unroll
  for (int j = 0; j < 2; ++j)
    fq[j] = load8(posb + (size_t)(q0 + 16 * j + c) * D_ + h * 32 + g * 8);

  // staging assignment: waves 0,1 stage K (chunks sg = dims), waves 2,3 stage V (sg = keychunk)
  const int kv = wid >> 1;                  // 0=K, 1=V
  const int sl = lane & 31;                 // key (K) or d (V)
  const int sg = (lane >> 5) + (wid & 1) * 2;  // chunk 0..3
  const ushort* ssrc = (kv == 0)
      ? (posb + (size_t)sl * D_ + h * 32 + sg * 8)   // K[key=sl][dims h*32+sg*8..+8]
      : (vtb + (size_t)sl * S_ + sg * 8);            // Vt[d=sl][keys sg*8..+8]
  const size_t sstep = (kv == 0) ? (size_t)(32 * D_) : (size_t)32;

  const f32x4 zero = {0.f, 0.f, 0.f, 0.f};
  f32x4 o0[2], o1[2], o2[2];
#pragma unroll
  for (int j = 0; j < 2; ++j) { o0[j] = zero; o1[j] = zero; o2[j] = zero; }

  const float C1 = 0.42044820762685725f * 1.44269504088896340f; // RS * log2e
  const float C2 = -16.0f * 1.44269504088896340f;               // -OFF * log2e

  // prologue: stage tile 0 into buf 0
  {
    bf16x8 st = load8(ssrc);
    *(uint4*)(&sbuf[0][kv][sg][sl][0]) = __builtin_bit_cast(uint4, st);
  }
  bf16x8 am = load8(mb);
  __syncthreads();

  int cur = 0;
  for (int t = 0; t < 64; ++t) {
    int tn = (t + 1) & 63;  // wraps; final stage unused
    bf16x8 nst = load8(ssrc + (size_t)tn * sstep);
    bf16x8 nm = load8(mb + tn * 32);

    // fragments from LDS (2-way bank aliasing only)
    bf16x8 ak0 = load8(&sbuf[cur][0][g][c][0]);
    bf16x8 ak1 = load8(&sbuf[cur][0][g][16 + c][0]);
    bf16x8 av0 = load8(&sbuf[cur][1][g][c][0]);
    bf16x8 av1 = load8(&sbuf[cur][1][g][16 + c][0]);

#pragma unroll
    for (int j = 0; j < 2; ++j) {
      f32x4 s0 = __builtin_amdgcn_mfma_f32_16x16x32_bf16(ak0, fq[j], zero, 0, 0, 0);
      f32x4 s1 = __builtin_amdgcn_mfma_f32_16x16x32_bf16(ak1, fq[j], zero, 0, 0, 0);

      float p0 = __builtin_amdgcn_exp2f(fmaf(s0[0], C1, C2));
      float p1 = __builtin_amdgcn_exp2f(fmaf(s0[1], C1, C2));
      float p2 = __builtin_amdgcn_exp2f(fmaf(s0[2], C1, C2));
      float p3 = __builtin_amdgcn_exp2f(fmaf(s0[3], C1, C2));
      float p4 = __builtin_amdgcn_exp2f(fmaf(s1[0], C1, C2));
      float p5 = __builtin_amdgcn_exp2f(fmaf(s1[1], C1, C2));
      float p6 = __builtin_amdgcn_exp2f(fmaf(s1[2], C1, C2));
      float p7 = __builtin_amdgcn_exp2f(fmaf(s1[3], C1, C2));

      uint4 uw = make_uint4(cvtpk(p0, p1), cvtpk(p2, p3), cvtpk(p4, p5), cvtpk(p6, p7));
      bf16x8 fp = __builtin_bit_cast(bf16x8, uw);

      o0[j] = __builtin_amdgcn_mfma_f32_16x16x32_bf16(fp, av0, o0[j], 0, 0, 0);
      o1[j] = __builtin_amdgcn_mfma_f32_16x16x32_bf16(fp, av1, o1[j], 0, 0, 0);
      o2[j] = __builtin_amdgcn_mfma_f32_16x16x32_bf16(fp, am, o2[j], 0, 0, 0);
    }

    // write next tile into the other buffer, then one barrier
    *(uint4*)(&sbuf[cur ^ 1][kv][sg][sl][0]) = __builtin_bit_cast(uint4, nst);
    __syncthreads();
    cur ^= 1;
    am = nm;
  }

  // epilogue: each wave owns its 32 q rows completely; o2[j][r] = lsum (same across c)
  ushort* ob = attnbf + (size_t)(b * S_ + q0) * D_ + h * 32;
#pragma unroll
  for (int j = 0; j < 2; ++j) {
#pragma unroll
    for (int r = 0; r < 4; ++r) {
      float ir = 1.f / o2[j][r];
      int row = 16 * j + 4 * g + r;
      ob[(size_t)row * D_ + c] = f2bf(o0[j][r] * ir);
      ob[(size_t)row * D_ + 16 + c] = f2bf(o1[j][r] * ir);
    }
  }
}

// ---- projection GEMM: out = relu(attn @ W + b) ----
__global__ __launch_bounds__(256) void proj_kernel(
    const ushort* __restrict__ attnbf,
    const ushort* __restrict__ wt,
    const float* __restrict__ bias,
    float* __restrict__ out) {
  const int tid = threadIdx.x;
  const int wid = tid >> 6, lane = tid & 63;
  const int c = lane & 15, g = lane >> 4;
  const int m0 = blockIdx.x * 64 + wid * 16;
  const int n0 = blockIdx.y * 64;

  f32x4 acc[4];
#pragma unroll
  for (int nb = 0; nb < 4; ++nb) acc[nb] = (f32x4){0.f, 0.f, 0.f, 0.f};

  for (int k0 = 0; k0 < D_; k0 += 32) {
    bf16x8 fa = load8(attnbf + (size_t)(m0 + c) * D_ + k0 + 8 * g);
#pragma unroll
    for (int nb = 0; nb < 4; ++nb) {
      bf16x8 fb = load8(wt + (size_t)(n0 + nb * 16 + c) * D_ + k0 + 8 * g);
      acc[nb] = __builtin_amdgcn_mfma_f32_16x16x32_bf16(fa, fb, acc[nb], 0, 0, 0);
    }
  }

#pragma unroll
  for (int nb = 0; nb < 4; ++nb) {
    int n = n0 + nb * 16 + c;
    float bv = bias[n];
#pragma unroll
    for (int r = 0; r < 4; ++r) {
      int mrow = m0 + 4 * g + r;
      float v = acc[nb][r] + bv;
      out[(size_t)mrow * D_ + n] = fmaxf(v, 0.f);
    }
  }
}

extern "C" void kernel_launch(void* const* d_in, const int* in_sizes, int n_in,
                              void* d_out, int out_size, void* d_ws, size_t ws_size,
                              hipStream_t stream) {
  const float* x = (const float*)d_in[0];     // [B,S,D]
  const float* mask = (const float*)d_in[1];  // [B,S,1]
  const float* pos = (const float*)d_in[2];   // [B,S,D]
  const float* W = (const float*)d_in[3];     // [D,D]
  const float* bias = (const float*)d_in[4];  // [D]
  float* out = (float*)d_out;

  const size_t NE = (size_t)B_ * S_ * D_;  // 2097152
  ushort* posbf = (ushort*)d_ws;
  ushort* vtbuf = posbf + NE;
  ushort* attnbf = vtbuf + NE;
  ushort* wtbuf = attnbf + NE;                 // D*D = 65536
  ushort* maskpbuf = wtbuf + (size_t)D_ * D_;  // B*S = 8192

  cvt_bf16_kernel<<<(int)(NE / 4 / 256), 256, 0, stream>>>(pos, posbf, (int)(NE / 4));
  build_vt_kernel<<<dim3(S_ / 32, B_ * H_), dim3(32, 32), 0, stream>>>(x, mask, vtbuf);
  build_maskp_kernel<<<(B_ * S_) / 256, 256, 0, stream>>>(mask, maskpbuf, B_ * S_);
  build_wt_kernel<<<dim3(D_ / 32, D_ / 32), dim3(32, 32), 0, stream>>>(W, wtbuf);
  attn_kernel<<<512, 256, 0, stream>>>(posbf, vtbuf, maskpbuf, attnbf);
  proj_kernel<<<dim3((B_ * S_) / 64, D_ / 64), 256, 0, stream>>>(attnbf, wtbuf, bias, out);
}

// Round 15
// 61.346 us; speedup vs baseline: 1.1678x; 1.1552x over previous
//
#include <hip/hip_runtime.h>
#include <hip/hip_bf16.h>
#include <math.h>

#define B_ 4
#define S_ 2048
#define D_ 256
#define H_ 8

typedef __attribute__((ext_vector_type(8))) __bf16 bf16x8;
typedef __attribute__((ext_vector_type(4))) float f32x4;

__device__ inline ushort f2bf(float x) {
  unsigned u = __builtin_bit_cast(unsigned, x);
  unsigned r = u + 0x7fffu + ((u >> 16) & 1u);
  return (ushort)(r >> 16);
}

__device__ inline float bf2f(ushort u) {
  unsigned v = ((unsigned)u) << 16;
  return __builtin_bit_cast(float, v);
}

__device__ inline unsigned cvtpk(float lo, float hi) {
  unsigned r;
  asm("v_cvt_pk_bf16_f32 %0, %1, %2" : "=v"(r) : "v"(lo), "v"(hi));
  return r;
}

__device__ inline bf16x8 load8(const ushort* p) {
  return __builtin_bit_cast(bf16x8, *(const uint4*)p);
}

// ---- prepass: f32 -> bf16 (pos) ----
__global__ void cvt_bf16_kernel(const float* __restrict__ in, ushort* __restrict__ out, int n4) {
  int i = blockIdx.x * blockDim.x + threadIdx.x;
  if (i >= n4) return;
  float4 v = ((const float4*)in)[i];
  ushort4 o;
  o.x = f2bf(v.x); o.y = f2bf(v.y); o.z = f2bf(v.z); o.w = f2bf(v.w);
  ((ushort4*)out)[i] = o;
}

// ---- prepass: Vt[bh][d][s], mask folded in, key-permuted columns per 32-tile ----
__global__ void build_vt_kernel(const float* __restrict__ x, const float* __restrict__ mask,
                                ushort* __restrict__ vt) {
  __shared__ ushort tile[32][33];
  int s0 = blockIdx.x * 32;
  int bh = blockIdx.y;
  int b = bh >> 3, h = bh & 7;
  int tx = threadIdx.x, ty = threadIdx.y;
  float mval = mask[b * S_ + s0 + ty];
  tile[ty][tx] = f2bf(x[((size_t)(b * S_ + s0 + ty)) * D_ + h * 32 + tx] * mval);
  __syncthreads();
  int kx = ((tx >> 1) & 12) + (tx & 3) + ((tx & 4) << 2);  // kappa(tx)
  vt[((size_t)bh * 32 + ty) * S_ + s0 + tx] = tile[kx][ty];
}

// ---- prepass: kappa-permuted bf16 mask ----
__global__ void build_maskp_kernel(const float* __restrict__ mask, ushort* __restrict__ maskp, int n) {
  int i = blockIdx.x * blockDim.x + threadIdx.x;
  if (i >= n) return;
  int t = i & 31;
  int kx = ((t >> 1) & 12) + (t & 3) + ((t & 4) << 2);
  maskp[i] = f2bf(mask[(i & ~31) + kx]);
}

// ---- prepass: Wt[n][k] = W[k][n] as bf16 ----
__global__ void build_wt_kernel(const float* __restrict__ w, ushort* __restrict__ wt) {
  __shared__ ushort tile[32][33];
  int k0 = blockIdx.x * 32;
  int n0 = blockIdx.y * 32;
  int tx = threadIdx.x, ty = threadIdx.y;
  tile[ty][tx] = f2bf(w[(k0 + ty) * D_ + n0 + tx]);
  __syncthreads();
  wt[(n0 + ty) * D_ + k0 + tx] = tile[tx][ty];
}

// ---- prepass: fragment-linearize K/V: frag[bh][T][slot][lane] = 16B fragment ----
// slot 0: K[T*32+c][h*32+g*8..]   slot 1: K[T*32+16+c][...]
// slot 2: Vt[bh][c][T*32+g*8..]   slot 3: Vt[bh][16+c][...]
__global__ __launch_bounds__(256) void build_frag_kernel(
    const ushort* __restrict__ posbf, const ushort* __restrict__ vt,
    ushort* __restrict__ frag) {
  int T = blockIdx.x;       // 0..63
  int bh = blockIdx.y;      // 0..31
  int b = bh >> 3, h = bh & 7;
  int slot = threadIdx.x >> 6;
  int lane = threadIdx.x & 63;
  int c = lane & 15, g = lane >> 4;
  const ushort* src;
  if (slot == 0)      src = posbf + (size_t)(b * S_ + T * 32 + c) * D_ + h * 32 + g * 8;
  else if (slot == 1) src = posbf + (size_t)(b * S_ + T * 32 + 16 + c) * D_ + h * 32 + g * 8;
  else if (slot == 2) src = vt + ((size_t)bh * 32 + c) * S_ + T * 32 + g * 8;
  else                src = vt + ((size_t)bh * 32 + 16 + c) * S_ + T * 32 + g * 8;
  uint4 v = *(const uint4*)src;
  *(uint4*)(frag + ((size_t)(bh * 64 + T) * 4 + slot) * 512 + lane * 8) = v;
}

// ---- flash attention (R9-green verbatim, loads redirected to dense frag stream) ----
__global__ __launch_bounds__(256, 3) void attn_kernel(
    const ushort* __restrict__ posbf,
    const ushort* __restrict__ frag,
    const ushort* __restrict__ maskp,
    ushort* __restrict__ attnbf) {
  __shared__ ushort lo[4][64][32];  // [wave][q][d] bf16 partial outputs
  __shared__ float ll[4][64];       // [wave][q] partial lsums (f32)
  __shared__ float linv[64];

  const int tid = threadIdx.x;
  const int wid = tid >> 6, lane = tid & 63;
  const int c = lane & 15, g = lane >> 4;
  const int blk = blockIdx.x;
  const int bh = blk & 31;   // XCD co-location
  const int qc = blk >> 5;   // 0..31
  const int b = bh >> 3, h = bh & 7;
  const int q0 = qc * 64;
  const int koff = wid * 512;  // this wave's key quarter

  const ushort* posb = posbf + (size_t)b * S_ * D_;

  // 4 Q fragments (B' operand): col j covers queries q0+16j+c
  bf16x8 fq[4];
#pragma unroll
  for (int j = 0; j < 4; ++j)
    fq[j] = load8(posb + (size_t)(q0 + 16 * j + c) * D_ + h * 32 + g * 8);

  // dense fragment stream: this wave's 16 tiles start at global tile wid*16
  const ushort* fragb = frag + ((size_t)bh * 64 + wid * 16) * 2048 + (size_t)lane * 8;
  const ushort* mb = maskp + (size_t)b * S_ + koff + g * 8;

  const f32x4 zero = {0.f, 0.f, 0.f, 0.f};
  f32x4 o0[4], o1[4], o2[4];
#pragma unroll
  for (int j = 0; j < 4; ++j) { o0[j] = zero; o1[j] = zero; o2[j] = zero; }

  const float C1 = 0.42044820762685725f * 1.44269504088896340f; // RS * log2e
  const float C2 = -16.0f * 1.44269504088896340f;               // -OFF * log2e

  bf16x8 ak0 = load8(fragb + 0 * 512);
  bf16x8 ak1 = load8(fragb + 1 * 512);
  bf16x8 av0 = load8(fragb + 2 * 512);
  bf16x8 av1 = load8(fragb + 3 * 512);
  bf16x8 am  = load8(mb);

  for (int t = 0; t < 16; ++t) {
    int tn = (t + 1) & 15;  // wraps; final reload unused
    const ushort* fn = fragb + (size_t)tn * 2048;
    bf16x8 nk0 = load8(fn + 0 * 512);
    bf16x8 nk1 = load8(fn + 1 * 512);
    bf16x8 nv0 = load8(fn + 2 * 512);
    bf16x8 nv1 = load8(fn + 3 * 512);
    bf16x8 nm  = load8(mb + tn * 32);

#pragma unroll
    for (int j = 0; j < 4; ++j) {
      f32x4 s0 = __builtin_amdgcn_mfma_f32_16x16x32_bf16(ak0, fq[j], zero, 0, 0, 0);
      f32x4 s1 = __builtin_amdgcn_mfma_f32_16x16x32_bf16(ak1, fq[j], zero, 0, 0, 0);

      float p0 = __builtin_amdgcn_exp2f(fmaf(s0[0], C1, C2));
      float p1 = __builtin_amdgcn_exp2f(fmaf(s0[1], C1, C2));
      float p2 = __builtin_amdgcn_exp2f(fmaf(s0[2], C1, C2));
      float p3 = __builtin_amdgcn_exp2f(fmaf(s0[3], C1, C2));
      float p4 = __builtin_amdgcn_exp2f(fmaf(s1[0], C1, C2));
      float p5 = __builtin_amdgcn_exp2f(fmaf(s1[1], C1, C2));
      float p6 = __builtin_amdgcn_exp2f(fmaf(s1[2], C1, C2));
      float p7 = __builtin_amdgcn_exp2f(fmaf(s1[3], C1, C2));

      uint4 uw = make_uint4(cvtpk(p0, p1), cvtpk(p2, p3), cvtpk(p4, p5), cvtpk(p6, p7));
      bf16x8 fp = __builtin_bit_cast(bf16x8, uw);

      o0[j] = __builtin_amdgcn_mfma_f32_16x16x32_bf16(fp, av0, o0[j], 0, 0, 0);
      o1[j] = __builtin_amdgcn_mfma_f32_16x16x32_bf16(fp, av1, o1[j], 0, 0, 0);
      o2[j] = __builtin_amdgcn_mfma_f32_16x16x32_bf16(fp, am, o2[j], 0, 0, 0);
    }

    ak0 = nk0; ak1 = nk1; av0 = nv0; av1 = nv1; am = nm;
  }

  // deposit wave partials to LDS (bf16)
#pragma unroll
  for (int j = 0; j < 4; ++j) {
#pragma unroll
    for (int r = 0; r < 4; ++r) {
      int ql = 16 * j + 4 * g + r;
      lo[wid][ql][c] = f2bf(o0[j][r]);
      lo[wid][ql][16 + c] = f2bf(o1[j][r]);
      if (c == 0) ll[wid][ql] = o2[j][r];
    }
  }
  __syncthreads();
  if (tid < 64) {
    float l = ll[0][tid] + ll[1][tid] + ll[2][tid] + ll[3][tid];
    linv[tid] = 1.f / l;
  }
  __syncthreads();

  // reduce 4 wave-partials and write bf16 output
  for (int e = tid; e < 64 * 32; e += 256) {
    int q = e >> 5, d = e & 31;
    float s = bf2f(lo[0][q][d]) + bf2f(lo[1][q][d]) + bf2f(lo[2][q][d]) + bf2f(lo[3][q][d]);
    attnbf[(size_t)(b * S_ + q0 + q) * D_ + h * 32 + d] = f2bf(s * linv[q]);
  }
}

// ---- projection GEMM: out = relu(attn @ W + b) ----
__global__ __launch_bounds__(256) void proj_kernel(
    const ushort* __restrict__ attnbf,
    const ushort* __restrict__ wt,
    const float* __restrict__ bias,
    float* __restrict__ out) {
  const int tid = threadIdx.x;
  const int wid = tid >> 6, lane = tid & 63;
  const int c = lane & 15, g = lane >> 4;
  const int m0 = blockIdx.x * 64 + wid * 16;
  const int n0 = blockIdx.y * 64;

  f32x4 acc[4];
#pragma unroll
  for (int nb = 0; nb < 4; ++nb) acc[nb] = (f32x4){0.f, 0.f, 0.f, 0.f};

  for (int k0 = 0; k0 < D_; k0 += 32) {
    bf16x8 fa = load8(attnbf + (size_t)(m0 + c) * D_ + k0 + 8 * g);
#pragma unroll
    for (int nb = 0; nb < 4; ++nb) {
      bf16x8 fb = load8(wt + (size_t)(n0 + nb * 16 + c) * D_ + k0 + 8 * g);
      acc[nb] = __builtin_amdgcn_mfma_f32_16x16x32_bf16(fa, fb, acc[nb], 0, 0, 0);
    }
  }

#pragma unroll
  for (int nb = 0; nb < 4; ++nb) {
    int n = n0 + nb * 16 + c;
    float bv = bias[n];
#pragma unroll
    for (int r = 0; r < 4; ++r) {
      int mrow = m0 + 4 * g + r;
      float v = acc[nb][r] + bv;
      out[(size_t)mrow * D_ + n] = fmaxf(v, 0.f);
    }
  }
}

extern "C" void kernel_launch(void* const* d_in, const int* in_sizes, int n_in,
                              void* d_out, int out_size, void* d_ws, size_t ws_size,
                              hipStream_t stream) {
  const float* x = (const float*)d_in[0];     // [B,S,D]
  const float* mask = (const float*)d_in[1];  // [B,S,1]
  const float* pos = (const float*)d_in[2];   // [B,S,D]
  const float* W = (const float*)d_in[3];     // [D,D]
  const float* bias = (const float*)d_in[4];  // [D]
  float* out = (float*)d_out;

  const size_t NE = (size_t)B_ * S_ * D_;  // 2097152
  // ws: posbf 4MB | vtbuf 4MB | attnbf 4MB | wtbuf 128KB | maskp 16KB | frag 8MB
  ushort* posbf = (ushort*)d_ws;
  ushort* vtbuf = posbf + NE;
  ushort* attnbf = vtbuf + NE;
  ushort* wtbuf = attnbf + NE;                 // D*D = 65536
  ushort* maskpbuf = wtbuf + (size_t)D_ * D_;  // B*S = 8192
  ushort* fragbuf = maskpbuf + (size_t)B_ * S_;  // 32*64*4*512 = 4194304

  cvt_bf16_kernel<<<(int)(NE / 4 / 256), 256, 0, stream>>>(pos, posbf, (int)(NE / 4));
  build_vt_kernel<<<dim3(S_ / 32, B_ * H_), dim3(32, 32), 0, stream>>>(x, mask, vtbuf);
  build_maskp_kernel<<<(B_ * S_) / 256, 256, 0, stream>>>(mask, maskpbuf, B_ * S_);
  build_wt_kernel<<<dim3(D_ / 32, D_ / 32), dim3(32, 32), 0, stream>>>(W, wtbuf);
  build_frag_kernel<<<dim3(64, 32), 256, 0, stream>>>(posbf, vtbuf, fragbuf);
  attn_kernel<<<1024, 256, 0, stream>>>(posbf, fragbuf, maskpbuf, attnbf);
  proj_kernel<<<dim3((B_ * S_) / 64, D_ / 64), 256, 0, stream>>>(attnbf, wtbuf, bias, out);
}

// Round 16
// 53.172 us; speedup vs baseline: 1.3473x; 1.1537x over previous
//
#include <hip/hip_runtime.h>
#include <hip/hip_bf16.h>
#include <math.h>

#define B_ 4
#define S_ 2048
#define D_ 256
#define H_ 8

typedef __attribute__((ext_vector_type(8))) __bf16 bf16x8;
typedef __attribute__((ext_vector_type(4))) float f32x4;

__device__ inline ushort f2bf(float x) {
  unsigned u = __builtin_bit_cast(unsigned, x);
  unsigned r = u + 0x7fffu + ((u >> 16) & 1u);
  return (ushort)(r >> 16);
}

__device__ inline float bf2f(ushort u) {
  unsigned v = ((unsigned)u) << 16;
  return __builtin_bit_cast(float, v);
}

__device__ inline unsigned cvtpk(float lo, float hi) {
  unsigned r;
  asm("v_cvt_pk_bf16_f32 %0, %1, %2" : "=v"(r) : "v"(lo), "v"(hi));
  return r;
}

__device__ inline bf16x8 load8(const ushort* p) {
  return __builtin_bit_cast(bf16x8, *(const uint4*)p);
}

// ---- unified prepass: one block per (T, bh) builds
//   posbf rows T*32..+32, col-slice h*32..+32  (f32->bf16 of pos)
//   frag K slots (0,1) and V slots (2,3) for tile T of head bh
//   maskp for tile T (h==0 blocks only)
// frag layout identical to green R15: frag[((bh*64+T)*4+slot)*512 + lane*8]
__global__ __launch_bounds__(256) void prep_kernel(
    const float* __restrict__ x, const float* __restrict__ mask,
    const float* __restrict__ pos,
    ushort* __restrict__ posbf, ushort* __restrict__ frag, ushort* __restrict__ maskp) {
  __shared__ float Lx[32][33];
  const int T = blockIdx.x, bh = blockIdx.y;
  const int b = bh >> 3, h = bh & 7;
  const int tid = threadIdx.x;
  const int slot = tid >> 6, lane = tid & 63;
  const int c = lane & 15, g = lane >> 4;
  const size_t rb = (size_t)(b * S_) + T * 32;  // global row base

  // (a) x * mask -> LDS f32 tile (rows = keys, cols = head dims)
  {
    int r0 = tid >> 5, cc = tid & 31;
#pragma unroll
    for (int k = 0; k < 4; ++k) {
      int r = r0 + 8 * k;
      Lx[r][cc] = x[(rb + r) * D_ + h * 32 + cc] * mask[rb + r];
    }
  }

  // (b) K slots: rows {c, 16+c}, dims g*8..+8 from pos (f32), convert, write frag + posbf
  if (slot < 2) {
    int row = slot * 16 + c;
    const float* ps = pos + (rb + row) * D_ + h * 32 + g * 8;
    float4 v0 = *(const float4*)ps;
    float4 v1 = *(const float4*)(ps + 4);
    uint4 fr;
    fr.x = (unsigned)f2bf(v0.x) | ((unsigned)f2bf(v0.y) << 16);
    fr.y = (unsigned)f2bf(v0.z) | ((unsigned)f2bf(v0.w) << 16);
    fr.z = (unsigned)f2bf(v1.x) | ((unsigned)f2bf(v1.y) << 16);
    fr.w = (unsigned)f2bf(v1.z) | ((unsigned)f2bf(v1.w) << 16);
    *(uint4*)(frag + ((size_t)(bh * 64 + T) * 4 + slot) * 512 + lane * 8) = fr;
    *(uint4*)(posbf + (rb + row) * D_ + h * 32 + g * 8) = fr;
  }

  __syncthreads();

  // (c) V slots: dcol = {c, 16+c}; elem i = Lx[kappa(g*8+i)][dcol]
  if (slot >= 2) {
    int dcol = (slot - 2) * 16 + c;
    ushort e[8];
#pragma unroll
    for (int i = 0; i < 8; ++i) {
      int key = (i < 4) ? (4 * g + i) : (16 + 4 * g + (i - 4));  // kappa(g*8+i)
      e[i] = f2bf(Lx[key][dcol]);
    }
    uint4 fr;
    fr.x = (unsigned)e[0] | ((unsigned)e[1] << 16);
    fr.y = (unsigned)e[2] | ((unsigned)e[3] << 16);
    fr.z = (unsigned)e[4] | ((unsigned)e[5] << 16);
    fr.w = (unsigned)e[6] | ((unsigned)e[7] << 16);
    *(uint4*)(frag + ((size_t)(bh * 64 + T) * 4 + slot) * 512 + lane * 8) = fr;
  }

  // (d) kappa-permuted bf16 mask (one writer per (b, T))
  if (h == 0 && tid < 32) {
    int t = tid;
    int kx = ((t >> 1) & 12) + (t & 3) + ((t & 4) << 2);
    maskp[rb + t] = f2bf(mask[rb + kx]);
  }
}

// ---- prepass: Wt[n][k] = W[k][n] as bf16 (green verbatim) ----
__global__ void build_wt_kernel(const float* __restrict__ w, ushort* __restrict__ wt) {
  __shared__ ushort tile[32][33];
  int k0 = blockIdx.x * 32;
  int n0 = blockIdx.y * 32;
  int tx = threadIdx.x, ty = threadIdx.y;
  tile[ty][tx] = f2bf(w[(k0 + ty) * D_ + n0 + tx]);
  __syncthreads();
  wt[(n0 + ty) * D_ + k0 + tx] = tile[tx][ty];
}

// ---- flash attention (green R15 verbatim) ----
__global__ __launch_bounds__(256, 3) void attn_kernel(
    const ushort* __restrict__ posbf,
    const ushort* __restrict__ frag,
    const ushort* __restrict__ maskp,
    ushort* __restrict__ attnbf) {
  __shared__ ushort lo[4][64][32];  // [wave][q][d] bf16 partial outputs
  __shared__ float ll[4][64];       // [wave][q] partial lsums (f32)
  __shared__ float linv[64];

  const int tid = threadIdx.x;
  const int wid = tid >> 6, lane = tid & 63;
  const int c = lane & 15, g = lane >> 4;
  const int blk = blockIdx.x;
  const int bh = blk & 31;   // XCD co-location
  const int qc = blk >> 5;   // 0..31
  const int b = bh >> 3, h = bh & 7;
  const int q0 = qc * 64;
  const int koff = wid * 512;  // this wave's key quarter

  const ushort* posb = posbf + (size_t)b * S_ * D_;

  // 4 Q fragments (B' operand): col j covers queries q0+16j+c
  bf16x8 fq[4];
#pragma unroll
  for (int j = 0; j < 4; ++j)
    fq[j] = load8(posb + (size_t)(q0 + 16 * j + c) * D_ + h * 32 + g * 8);

  // dense fragment stream: this wave's 16 tiles start at global tile wid*16
  const ushort* fragb = frag + ((size_t)bh * 64 + wid * 16) * 2048 + (size_t)lane * 8;
  const ushort* mb = maskp + (size_t)b * S_ + koff + g * 8;

  const f32x4 zero = {0.f, 0.f, 0.f, 0.f};
  f32x4 o0[4], o1[4], o2[4];
#pragma unroll
  for (int j = 0; j < 4; ++j) { o0[j] = zero; o1[j] = zero; o2[j] = zero; }

  const float C1 = 0.42044820762685725f * 1.44269504088896340f; // RS * log2e
  const float C2 = -16.0f * 1.44269504088896340f;               // -OFF * log2e

  bf16x8 ak0 = load8(fragb + 0 * 512);
  bf16x8 ak1 = load8(fragb + 1 * 512);
  bf16x8 av0 = load8(fragb + 2 * 512);
  bf16x8 av1 = load8(fragb + 3 * 512);
  bf16x8 am  = load8(mb);

  for (int t = 0; t < 16; ++t) {
    int tn = (t + 1) & 15;  // wraps; final reload unused
    const ushort* fn = fragb + (size_t)tn * 2048;
    bf16x8 nk0 = load8(fn + 0 * 512);
    bf16x8 nk1 = load8(fn + 1 * 512);
    bf16x8 nv0 = load8(fn + 2 * 512);
    bf16x8 nv1 = load8(fn + 3 * 512);
    bf16x8 nm  = load8(mb + tn * 32);

#pragma unroll
    for (int j = 0; j < 4; ++j) {
      f32x4 s0 = __builtin_amdgcn_mfma_f32_16x16x32_bf16(ak0, fq[j], zero, 0, 0, 0);
      f32x4 s1 = __builtin_amdgcn_mfma_f32_16x16x32_bf16(ak1, fq[j], zero, 0, 0, 0);

      float p0 = __builtin_amdgcn_exp2f(fmaf(s0[0], C1, C2));
      float p1 = __builtin_amdgcn_exp2f(fmaf(s0[1], C1, C2));
      float p2 = __builtin_amdgcn_exp2f(fmaf(s0[2], C1, C2));
      float p3 = __builtin_amdgcn_exp2f(fmaf(s0[3], C1, C2));
      float p4 = __builtin_amdgcn_exp2f(fmaf(s1[0], C1, C2));
      float p5 = __builtin_amdgcn_exp2f(fmaf(s1[1], C1, C2));
      float p6 = __builtin_amdgcn_exp2f(fmaf(s1[2], C1, C2));
      float p7 = __builtin_amdgcn_exp2f(fmaf(s1[3], C1, C2));

      uint4 uw = make_uint4(cvtpk(p0, p1), cvtpk(p2, p3), cvtpk(p4, p5), cvtpk(p6, p7));
      bf16x8 fp = __builtin_bit_cast(bf16x8, uw);

      o0[j] = __builtin_amdgcn_mfma_f32_16x16x32_bf16(fp, av0, o0[j], 0, 0, 0);
      o1[j] = __builtin_amdgcn_mfma_f32_16x16x32_bf16(fp, av1, o1[j], 0, 0, 0);
      o2[j] = __builtin_amdgcn_mfma_f32_16x16x32_bf16(fp, am, o2[j], 0, 0, 0);
    }

    ak0 = nk0; ak1 = nk1; av0 = nv0; av1 = nv1; am = nm;
  }

  // deposit wave partials to LDS (bf16)
#pragma unroll
  for (int j = 0; j < 4; ++j) {
#pragma unroll
    for (int r = 0; r < 4; ++r) {
      int ql = 16 * j + 4 * g + r;
      lo[wid][ql][c] = f2bf(o0[j][r]);
      lo[wid][ql][16 + c] = f2bf(o1[j][r]);
      if (c == 0) ll[wid][ql] = o2[j][r];
    }
  }
  __syncthreads();
  if (tid < 64) {
    float l = ll[0][tid] + ll[1][tid] + ll[2][tid] + ll[3][tid];
    linv[tid] = 1.f / l;
  }
  __syncthreads();

  // reduce 4 wave-partials and write bf16 output
  for (int e = tid; e < 64 * 32; e += 256) {
    int q = e >> 5, d = e & 31;
    float s = bf2f(lo[0][q][d]) + bf2f(lo[1][q][d]) + bf2f(lo[2][q][d]) + bf2f(lo[3][q][d]);
    attnbf[(size_t)(b * S_ + q0 + q) * D_ + h * 32 + d] = f2bf(s * linv[q]);
  }
}

// ---- projection GEMM: out = relu(attn @ W + b) (green verbatim) ----
__global__ __launch_bounds__(256) void proj_kernel(
    const ushort* __restrict__ attnbf,
    const ushort* __restrict__ wt,
    const float* __restrict__ bias,
    float* __restrict__ out) {
  const int tid = threadIdx.x;
  const int wid = tid >> 6, lane = tid & 63;
  const int c = lane & 15, g = lane >> 4;
  const int m0 = blockIdx.x * 64 + wid * 16;
  const int n0 = blockIdx.y * 64;

  f32x4 acc[4];
#pragma unroll
  for (int nb = 0; nb < 4; ++nb) acc[nb] = (f32x4){0.f, 0.f, 0.f, 0.f};

  for (int k0 = 0; k0 < D_; k0 += 32) {
    bf16x8 fa = load8(attnbf + (size_t)(m0 + c) * D_ + k0 + 8 * g);
#pragma unroll
    for (int nb = 0; nb < 4; ++nb) {
      bf16x8 fb = load8(wt + (size_t)(n0 + nb * 16 + c) * D_ + k0 + 8 * g);
      acc[nb] = __builtin_amdgcn_mfma_f32_16x16x32_bf16(fa, fb, acc[nb], 0, 0, 0);
    }
  }

#pragma unroll
  for (int nb = 0; nb < 4; ++nb) {
    int n = n0 + nb * 16 + c;
    float bv = bias[n];
#pragma unroll
    for (int r = 0; r < 4; ++r) {
      int mrow = m0 + 4 * g + r;
      float v = acc[nb][r] + bv;
      out[(size_t)mrow * D_ + n] = fmaxf(v, 0.f);
    }
  }
}

extern "C" void kernel_launch(void* const* d_in, const int* in_sizes, int n_in,
                              void* d_out, int out_size, void* d_ws, size_t ws_size,
                              hipStream_t stream) {
  const float* x = (const float*)d_in[0];     // [B,S,D]
  const float* mask = (const float*)d_in[1];  // [B,S,1]
  const float* pos = (const float*)d_in[2];   // [B,S,D]
  const float* W = (const float*)d_in[3];     // [D,D]
  const float* bias = (const float*)d_in[4];  // [D]
  float* out = (float*)d_out;

  const size_t NE = (size_t)B_ * S_ * D_;  // 2097152
  // ws: posbf 4MB | frag 8MB | attnbf 4MB | wtbuf 128KB | maskp 16KB
  ushort* posbf = (ushort*)d_ws;
  ushort* fragbuf = posbf + NE;                     // 32*64*4*512 = 4194304
  ushort* attnbf = fragbuf + (size_t)4194304;
  ushort* wtbuf = attnbf + NE;                      // D*D = 65536
  ushort* maskpbuf = wtbuf + (size_t)D_ * D_;       // B*S = 8192

  prep_kernel<<<dim3(64, 32), 256, 0, stream>>>(x, mask, pos, posbf, fragbuf, maskpbuf);
  build_wt_kernel<<<dim3(D_ / 32, D_ / 32), dim3(32, 32), 0, stream>>>(W, wtbuf);
  attn_kernel<<<1024, 256, 0, stream>>>(posbf, fragbuf, maskpbuf, attnbf);
  proj_kernel<<<dim3((B_ * S_) / 64, D_ / 64), 256, 0, stream>>>(attnbf, wtbuf, bias, out);
}

// Round 17
// 47.171 us; speedup vs baseline: 1.5186x; 1.1272x over previous
//
#include <hip/hip_runtime.h>
#include <hip/hip_bf16.h>
#include <math.h>

#define B_ 4
#define S_ 2048
#define D_ 256
#define H_ 8

typedef __attribute__((ext_vector_type(8))) __bf16 bf16x8;
typedef __attribute__((ext_vector_type(4))) float f32x4;

__device__ inline ushort f2bf(float x) {
  unsigned u = __builtin_bit_cast(unsigned, x);
  unsigned r = u + 0x7fffu + ((u >> 16) & 1u);
  return (ushort)(r >> 16);
}

__device__ inline float bf2f(ushort u) {
  unsigned v = ((unsigned)u) << 16;
  return __builtin_bit_cast(float, v);
}

__device__ inline unsigned cvtpk(float lo, float hi) {
  unsigned r;
  asm("v_cvt_pk_bf16_f32 %0, %1, %2" : "=v"(r) : "v"(lo), "v"(hi));
  return r;
}

__device__ inline bf16x8 load8(const ushort* p) {
  return __builtin_bit_cast(bf16x8, *(const uint4*)p);
}

// ---- unified prepass (green R16 verbatim) ----
__global__ __launch_bounds__(256) void prep_kernel(
    const float* __restrict__ x, const float* __restrict__ mask,
    const float* __restrict__ pos,
    ushort* __restrict__ posbf, ushort* __restrict__ frag, ushort* __restrict__ maskp) {
  __shared__ float Lx[32][33];
  const int T = blockIdx.x, bh = blockIdx.y;
  const int b = bh >> 3, h = bh & 7;
  const int tid = threadIdx.x;
  const int slot = tid >> 6, lane = tid & 63;
  const int c = lane & 15, g = lane >> 4;
  const size_t rb = (size_t)(b * S_) + T * 32;  // global row base

  // (a) x * mask -> LDS f32 tile
  {
    int r0 = tid >> 5, cc = tid & 31;
#pragma unroll
    for (int k = 0; k < 4; ++k) {
      int r = r0 + 8 * k;
      Lx[r][cc] = x[(rb + r) * D_ + h * 32 + cc] * mask[rb + r];
    }
  }

  // (b) K slots
  if (slot < 2) {
    int row = slot * 16 + c;
    const float* ps = pos + (rb + row) * D_ + h * 32 + g * 8;
    float4 v0 = *(const float4*)ps;
    float4 v1 = *(const float4*)(ps + 4);
    uint4 fr;
    fr.x = (unsigned)f2bf(v0.x) | ((unsigned)f2bf(v0.y) << 16);
    fr.y = (unsigned)f2bf(v0.z) | ((unsigned)f2bf(v0.w) << 16);
    fr.z = (unsigned)f2bf(v1.x) | ((unsigned)f2bf(v1.y) << 16);
    fr.w = (unsigned)f2bf(v1.z) | ((unsigned)f2bf(v1.w) << 16);
    *(uint4*)(frag + ((size_t)(bh * 64 + T) * 4 + slot) * 512 + lane * 8) = fr;
    *(uint4*)(posbf + (rb + row) * D_ + h * 32 + g * 8) = fr;
  }

  __syncthreads();

  // (c) V slots
  if (slot >= 2) {
    int dcol = (slot - 2) * 16 + c;
    ushort e[8];
#pragma unroll
    for (int i = 0; i < 8; ++i) {
      int key = (i < 4) ? (4 * g + i) : (16 + 4 * g + (i - 4));  // kappa(g*8+i)
      e[i] = f2bf(Lx[key][dcol]);
    }
    uint4 fr;
    fr.x = (unsigned)e[0] | ((unsigned)e[1] << 16);
    fr.y = (unsigned)e[2] | ((unsigned)e[3] << 16);
    fr.z = (unsigned)e[4] | ((unsigned)e[5] << 16);
    fr.w = (unsigned)e[6] | ((unsigned)e[7] << 16);
    *(uint4*)(frag + ((size_t)(bh * 64 + T) * 4 + slot) * 512 + lane * 8) = fr;
  }

  // (d) kappa-permuted bf16 mask
  if (h == 0 && tid < 32) {
    int t = tid;
    int kx = ((t >> 1) & 12) + (t & 3) + ((t & 4) << 2);
    maskp[rb + t] = f2bf(mask[rb + kx]);
  }
}

// ---- prepass: W fragment-linearized: wfrag[(nt*8+ks)*64+lane] = B-fragment 16B ----
// elem i = W[ks*32+g*8+i][nt*16+c]  (== green wt[nt*16+c][ks*32+g*8+i])
__global__ void build_wtf_kernel(const float* __restrict__ w, ushort* __restrict__ wfrag) {
  __shared__ ushort tile[32][33];
  int ks = blockIdx.x;           // k-tile 0..7
  int n0 = blockIdx.y * 32;      // n-pair base
  int k0 = ks * 32;
  int tx = threadIdx.x, ty = threadIdx.y;
  tile[ty][tx] = f2bf(w[(k0 + ty) * D_ + n0 + tx]);
  __syncthreads();
  int tid2 = ty * 32 + tx;
  if (tid2 < 128) {
    int sub = tid2 >> 6, lane = tid2 & 63;
    int c = lane & 15, g = lane >> 4;
    int nt = (n0 >> 4) + sub;
    ushort e[8];
#pragma unroll
    for (int i = 0; i < 8; ++i) e[i] = tile[g * 8 + i][sub * 16 + c];
    uint4 fr;
    fr.x = (unsigned)e[0] | ((unsigned)e[1] << 16);
    fr.y = (unsigned)e[2] | ((unsigned)e[3] << 16);
    fr.z = (unsigned)e[4] | ((unsigned)e[5] << 16);
    fr.w = (unsigned)e[6] | ((unsigned)e[7] << 16);
    *(uint4*)(wfrag + ((size_t)(nt * 8 + ks) * 64 + lane) * 8) = fr;
  }
}

// ---- flash attention (green R16 verbatim) ----
__global__ __launch_bounds__(256, 3) void attn_kernel(
    const ushort* __restrict__ posbf,
    const ushort* __restrict__ frag,
    const ushort* __restrict__ maskp,
    ushort* __restrict__ attnbf) {
  __shared__ ushort lo[4][64][32];
  __shared__ float ll[4][64];
  __shared__ float linv[64];

  const int tid = threadIdx.x;
  const int wid = tid >> 6, lane = tid & 63;
  const int c = lane & 15, g = lane >> 4;
  const int blk = blockIdx.x;
  const int bh = blk & 31;
  const int qc = blk >> 5;
  const int b = bh >> 3, h = bh & 7;
  const int q0 = qc * 64;
  const int koff = wid * 512;

  const ushort* posb = posbf + (size_t)b * S_ * D_;

  bf16x8 fq[4];
#pragma unroll
  for (int j = 0; j < 4; ++j)
    fq[j] = load8(posb + (size_t)(q0 + 16 * j + c) * D_ + h * 32 + g * 8);

  const ushort* fragb = frag + ((size_t)bh * 64 + wid * 16) * 2048 + (size_t)lane * 8;
  const ushort* mb = maskp + (size_t)b * S_ + koff + g * 8;

  const f32x4 zero = {0.f, 0.f, 0.f, 0.f};
  f32x4 o0[4], o1[4], o2[4];
#pragma unroll
  for (int j = 0; j < 4; ++j) { o0[j] = zero; o1[j] = zero; o2[j] = zero; }

  const float C1 = 0.42044820762685725f * 1.44269504088896340f;
  const float C2 = -16.0f * 1.44269504088896340f;

  bf16x8 ak0 = load8(fragb + 0 * 512);
  bf16x8 ak1 = load8(fragb + 1 * 512);
  bf16x8 av0 = load8(fragb + 2 * 512);
  bf16x8 av1 = load8(fragb + 3 * 512);
  bf16x8 am  = load8(mb);

  for (int t = 0; t < 16; ++t) {
    int tn = (t + 1) & 15;
    const ushort* fn = fragb + (size_t)tn * 2048;
    bf16x8 nk0 = load8(fn + 0 * 512);
    bf16x8 nk1 = load8(fn + 1 * 512);
    bf16x8 nv0 = load8(fn + 2 * 512);
    bf16x8 nv1 = load8(fn + 3 * 512);
    bf16x8 nm  = load8(mb + tn * 32);

#pragma unroll
    for (int j = 0; j < 4; ++j) {
      f32x4 s0 = __builtin_amdgcn_mfma_f32_16x16x32_bf16(ak0, fq[j], zero, 0, 0, 0);
      f32x4 s1 = __builtin_amdgcn_mfma_f32_16x16x32_bf16(ak1, fq[j], zero, 0, 0, 0);

      float p0 = __builtin_amdgcn_exp2f(fmaf(s0[0], C1, C2));
      float p1 = __builtin_amdgcn_exp2f(fmaf(s0[1], C1, C2));
      float p2 = __builtin_amdgcn_exp2f(fmaf(s0[2], C1, C2));
      float p3 = __builtin_amdgcn_exp2f(fmaf(s0[3], C1, C2));
      float p4 = __builtin_amdgcn_exp2f(fmaf(s1[0], C1, C2));
      float p5 = __builtin_amdgcn_exp2f(fmaf(s1[1], C1, C2));
      float p6 = __builtin_amdgcn_exp2f(fmaf(s1[2], C1, C2));
      float p7 = __builtin_amdgcn_exp2f(fmaf(s1[3], C1, C2));

      uint4 uw = make_uint4(cvtpk(p0, p1), cvtpk(p2, p3), cvtpk(p4, p5), cvtpk(p6, p7));
      bf16x8 fp = __builtin_bit_cast(bf16x8, uw);

      o0[j] = __builtin_amdgcn_mfma_f32_16x16x32_bf16(fp, av0, o0[j], 0, 0, 0);
      o1[j] = __builtin_amdgcn_mfma_f32_16x16x32_bf16(fp, av1, o1[j], 0, 0, 0);
      o2[j] = __builtin_amdgcn_mfma_f32_16x16x32_bf16(fp, am, o2[j], 0, 0, 0);
    }

    ak0 = nk0; ak1 = nk1; av0 = nv0; av1 = nv1; am = nm;
  }

#pragma unroll
  for (int j = 0; j < 4; ++j) {
#pragma unroll
    for (int r = 0; r < 4; ++r) {
      int ql = 16 * j + 4 * g + r;
      lo[wid][ql][c] = f2bf(o0[j][r]);
      lo[wid][ql][16 + c] = f2bf(o1[j][r]);
      if (c == 0) ll[wid][ql] = o2[j][r];
    }
  }
  __syncthreads();
  if (tid < 64) {
    float l = ll[0][tid] + ll[1][tid] + ll[2][tid] + ll[3][tid];
    linv[tid] = 1.f / l;
  }
  __syncthreads();

  for (int e = tid; e < 64 * 32; e += 256) {
    int q = e >> 5, d = e & 31;
    float s = bf2f(lo[0][q][d]) + bf2f(lo[1][q][d]) + bf2f(lo[2][q][d]) + bf2f(lo[3][q][d]);
    attnbf[(size_t)(b * S_ + q0 + q) * D_ + h * 32 + d] = f2bf(s * linv[q]);
  }
}

// ---- projection GEMM v2: LDS-staged A panel + fragment-linear W ----
__global__ __launch_bounds__(256) void proj_kernel(
    const ushort* __restrict__ attnbf,
    const ushort* __restrict__ wfrag,
    const float* __restrict__ bias,
    float* __restrict__ out) {
  __shared__ __align__(16) ushort sA[64][264];  // 64 rows x 256 dims, +8 pad

  const int tid = threadIdx.x;
  const int wid = tid >> 6, lane = tid & 63;
  const int c = lane & 15, g = lane >> 4;
  const int mb0 = blockIdx.x * 64;     // block's A-panel rows
  const int m0 = mb0 + wid * 16;       // this wave's rows
  const int n0 = blockIdx.y * 64;

  // stage A panel coalesced: 64 rows x 32 uint4
#pragma unroll
  for (int it = 0; it < 8; ++it) {
    int idx = tid + it * 256;          // 0..2047
    int row = idx >> 5, c8 = idx & 31;
    uint4 v = *(const uint4*)(attnbf + (size_t)(mb0 + row) * D_ + c8 * 8);
    *(uint4*)(&sA[row][c8 * 8]) = v;
  }
  __syncthreads();

  f32x4 acc[4];
#pragma unroll
  for (int nb = 0; nb < 4; ++nb) acc[nb] = (f32x4){0.f, 0.f, 0.f, 0.f};

#pragma unroll
  for (int ks = 0; ks < 8; ++ks) {
    bf16x8 fa = load8(&sA[wid * 16 + c][ks * 32 + 8 * g]);
#pragma unroll
    for (int nb = 0; nb < 4; ++nb) {
      int nt = (n0 >> 4) + nb;
      bf16x8 fb = load8(wfrag + ((size_t)(nt * 8 + ks) * 64 + lane) * 8);
      acc[nb] = __builtin_amdgcn_mfma_f32_16x16x32_bf16(fa, fb, acc[nb], 0, 0, 0);
    }
  }

#pragma unroll
  for (int nb = 0; nb < 4; ++nb) {
    int n = n0 + nb * 16 + c;
    float bv = bias[n];
#pragma unroll
    for (int r = 0; r < 4; ++r) {
      int mrow = m0 + 4 * g + r;
      float v = acc[nb][r] + bv;
      out[(size_t)mrow * D_ + n] = fmaxf(v, 0.f);
    }
  }
}

extern "C" void kernel_launch(void* const* d_in, const int* in_sizes, int n_in,
                              void* d_out, int out_size, void* d_ws, size_t ws_size,
                              hipStream_t stream) {
  const float* x = (const float*)d_in[0];     // [B,S,D]
  const float* mask = (const float*)d_in[1];  // [B,S,1]
  const float* pos = (const float*)d_in[2];   // [B,S,D]
  const float* W = (const float*)d_in[3];     // [D,D]
  const float* bias = (const float*)d_in[4];  // [D]
  float* out = (float*)d_out;

  const size_t NE = (size_t)B_ * S_ * D_;  // 2097152
  // ws: posbf 4MB | frag 8MB | attnbf 4MB | wfrag 128KB | maskp 16KB
  ushort* posbf = (ushort*)d_ws;
  ushort* fragbuf = posbf + NE;                     // 4194304 elems
  ushort* attnbf = fragbuf + (size_t)4194304;
  ushort* wfragbuf = attnbf + NE;                   // D*D = 65536
  ushort* maskpbuf = wfragbuf + (size_t)D_ * D_;    // B*S = 8192

  prep_kernel<<<dim3(64, 32), 256, 0, stream>>>(x, mask, pos, posbf, fragbuf, maskpbuf);
  build_wtf_kernel<<<dim3(D_ / 32, D_ / 32), dim3(32, 32), 0, stream>>>(W, wfragbuf);
  attn_kernel<<<1024, 256, 0, stream>>>(posbf, fragbuf, maskpbuf, attnbf);
  proj_kernel<<<dim3((B_ * S_) / 64, D_ / 64), 256, 0, stream>>>(attnbf, wfragbuf, bias, out);
}

// Round 20
// 45.002 us; speedup vs baseline: 1.5918x; 1.0482x over previous
//
#include <hip/hip_runtime.h>
#include <hip/hip_bf16.h>
#include <math.h>

#define B_ 4
#define S_ 2048
#define D_ 256
#define H_ 8

typedef __attribute__((ext_vector_type(8))) __bf16 bf16x8;
typedef __attribute__((ext_vector_type(4))) float f32x4;

__device__ inline ushort f2bf(float x) {
  unsigned u = __builtin_bit_cast(unsigned, x);
  unsigned r = u + 0x7fffu + ((u >> 16) & 1u);
  return (ushort)(r >> 16);
}

__device__ inline float bf2f(ushort u) {
  unsigned v = ((unsigned)u) << 16;
  return __builtin_bit_cast(float, v);
}

__device__ inline unsigned cvtpk(float lo, float hi) {
  unsigned r;
  asm("v_cvt_pk_bf16_f32 %0, %1, %2" : "=v"(r) : "v"(lo), "v"(hi));
  return r;
}

__device__ inline bf16x8 load8(const ushort* p) {
  return __builtin_bit_cast(bf16x8, *(const uint4*)p);
}

// ---- unified prepass: grid (64, 33).
//  bh<32 : green R16 prep verbatim (posbf, frag K/V, maskp)
//  bh==32: W fragment tile T (ks=T&7, np=T>>3) -> wfrag, green build_wtf indexing
__global__ __launch_bounds__(256) void prep_kernel(
    const float* __restrict__ x, const float* __restrict__ mask,
    const float* __restrict__ pos, const float* __restrict__ w,
    ushort* __restrict__ posbf, ushort* __restrict__ frag,
    ushort* __restrict__ maskp, ushort* __restrict__ wfrag) {
  __shared__ float Lx[32][33];
  __shared__ ushort Wt[32][33];
  const int T = blockIdx.x, bh = blockIdx.y;
  const int tid = threadIdx.x;

  if (bh == 32) {
    int ks = T & 7, np = T >> 3;
    int k0 = ks * 32, n0 = np * 32;
#pragma unroll
    for (int k = 0; k < 4; ++k) {
      int idx = tid + k * 256;  // 0..1023
      int ty = idx >> 5, tx = idx & 31;
      Wt[ty][tx] = f2bf(w[(k0 + ty) * D_ + n0 + tx]);
    }
    __syncthreads();
    if (tid < 128) {
      int sub = tid >> 6, lane = tid & 63;
      int c = lane & 15, g = lane >> 4;
      int nt = np * 2 + sub;
      ushort e[8];
#pragma unroll
      for (int i = 0; i < 8; ++i) e[i] = Wt[g * 8 + i][sub * 16 + c];
      uint4 fr;
      fr.x = (unsigned)e[0] | ((unsigned)e[1] << 16);
      fr.y = (unsigned)e[2] | ((unsigned)e[3] << 16);
      fr.z = (unsigned)e[4] | ((unsigned)e[5] << 16);
      fr.w = (unsigned)e[6] | ((unsigned)e[7] << 16);
      *(uint4*)(wfrag + ((size_t)(nt * 8 + ks) * 64 + lane) * 8) = fr;
    }
    return;
  }

  const int b = bh >> 3, h = bh & 7;
  const int slot = tid >> 6, lane = tid & 63;
  const int c = lane & 15, g = lane >> 4;
  const size_t rb = (size_t)(b * S_) + T * 32;  // global row base

  // (a) x * mask -> LDS f32 tile
  {
    int r0 = tid >> 5, cc = tid & 31;
#pragma unroll
    for (int k = 0; k < 4; ++k) {
      int r = r0 + 8 * k;
      Lx[r][cc] = x[(rb + r) * D_ + h * 32 + cc] * mask[rb + r];
    }
  }

  // (b) K slots
  if (slot < 2) {
    int row = slot * 16 + c;
    const float* ps = pos + (rb + row) * D_ + h * 32 + g * 8;
    float4 v0 = *(const float4*)ps;
    float4 v1 = *(const float4*)(ps + 4);
    uint4 fr;
    fr.x = (unsigned)f2bf(v0.x) | ((unsigned)f2bf(v0.y) << 16);
    fr.y = (unsigned)f2bf(v0.z) | ((unsigned)f2bf(v0.w) << 16);
    fr.z = (unsigned)f2bf(v1.x) | ((unsigned)f2bf(v1.y) << 16);
    fr.w = (unsigned)f2bf(v1.z) | ((unsigned)f2bf(v1.w) << 16);
    *(uint4*)(frag + ((size_t)(bh * 64 + T) * 4 + slot) * 512 + lane * 8) = fr;
    *(uint4*)(posbf + (rb + row) * D_ + h * 32 + g * 8) = fr;
  }

  __syncthreads();

  // (c) V slots
  if (slot >= 2) {
    int dcol = (slot - 2) * 16 + c;
    ushort e[8];
#pragma unroll
    for (int i = 0; i < 8; ++i) {
      int key = (i < 4) ? (4 * g + i) : (16 + 4 * g + (i - 4));  // kappa(g*8+i)
      e[i] = f2bf(Lx[key][dcol]);
    }
    uint4 fr;
    fr.x = (unsigned)e[0] | ((unsigned)e[1] << 16);
    fr.y = (unsigned)e[2] | ((unsigned)e[3] << 16);
    fr.z = (unsigned)e[4] | ((unsigned)e[5] << 16);
    fr.w = (unsigned)e[6] | ((unsigned)e[7] << 16);
    *(uint4*)(frag + ((size_t)(bh * 64 + T) * 4 + slot) * 512 + lane * 8) = fr;
  }

  // (d) kappa-permuted bf16 mask
  if (h == 0 && tid < 32) {
    int t = tid;
    int kx = ((t >> 1) & 12) + (t & 3) + ((t & 4) << 2);
    maskp[rb + t] = f2bf(mask[rb + kx]);
  }
}

// ---- flash attention (green R16 verbatim, depth-1 prefetch) ----
__global__ __launch_bounds__(256, 3) void attn_kernel(
    const ushort* __restrict__ posbf,
    const ushort* __restrict__ frag,
    const ushort* __restrict__ maskp,
    ushort* __restrict__ attnbf) {
  __shared__ ushort lo[4][64][32];
  __shared__ float ll[4][64];
  __shared__ float linv[64];

  const int tid = threadIdx.x;
  const int wid = tid >> 6, lane = tid & 63;
  const int c = lane & 15, g = lane >> 4;
  const int blk = blockIdx.x;
  const int bh = blk & 31;
  const int qc = blk >> 5;
  const int b = bh >> 3, h = bh & 7;
  const int q0 = qc * 64;
  const int koff = wid * 512;

  const ushort* posb = posbf + (size_t)b * S_ * D_;

  bf16x8 fq[4];
#pragma unroll
  for (int j = 0; j < 4; ++j)
    fq[j] = load8(posb + (size_t)(q0 + 16 * j + c) * D_ + h * 32 + g * 8);

  const ushort* fragb = frag + ((size_t)bh * 64 + wid * 16) * 2048 + (size_t)lane * 8;
  const ushort* mb = maskp + (size_t)b * S_ + koff + g * 8;

  const f32x4 zero = {0.f, 0.f, 0.f, 0.f};
  f32x4 o0[4], o1[4], o2[4];
#pragma unroll
  for (int j = 0; j < 4; ++j) { o0[j] = zero; o1[j] = zero; o2[j] = zero; }

  const float C1 = 0.42044820762685725f * 1.44269504088896340f;
  const float C2 = -16.0f * 1.44269504088896340f;

  bf16x8 ak0 = load8(fragb + 0 * 512);
  bf16x8 ak1 = load8(fragb + 1 * 512);
  bf16x8 av0 = load8(fragb + 2 * 512);
  bf16x8 av1 = load8(fragb + 3 * 512);
  bf16x8 am  = load8(mb);

  for (int t = 0; t < 16; ++t) {
    int tn = (t + 1) & 15;
    const ushort* fn = fragb + (size_t)tn * 2048;
    bf16x8 nk0 = load8(fn + 0 * 512);
    bf16x8 nk1 = load8(fn + 1 * 512);
    bf16x8 nv0 = load8(fn + 2 * 512);
    bf16x8 nv1 = load8(fn + 3 * 512);
    bf16x8 nm  = load8(mb + tn * 32);

#pragma unroll
    for (int j = 0; j < 4; ++j) {
      f32x4 s0 = __builtin_amdgcn_mfma_f32_16x16x32_bf16(ak0, fq[j], zero, 0, 0, 0);
      f32x4 s1 = __builtin_amdgcn_mfma_f32_16x16x32_bf16(ak1, fq[j], zero, 0, 0, 0);

      float p0 = __builtin_amdgcn_exp2f(fmaf(s0[0], C1, C2));
      float p1 = __builtin_amdgcn_exp2f(fmaf(s0[1], C1, C2));
      float p2 = __builtin_amdgcn_exp2f(fmaf(s0[2], C1, C2));
      float p3 = __builtin_amdgcn_exp2f(fmaf(s0[3], C1, C2));
      float p4 = __builtin_amdgcn_exp2f(fmaf(s1[0], C1, C2));
      float p5 = __builtin_amdgcn_exp2f(fmaf(s1[1], C1, C2));
      float p6 = __builtin_amdgcn_exp2f(fmaf(s1[2], C1, C2));
      float p7 = __builtin_amdgcn_exp2f(fmaf(s1[3], C1, C2));

      uint4 uw = make_uint4(cvtpk(p0, p1), cvtpk(p2, p3), cvtpk(p4, p5), cvtpk(p6, p7));
      bf16x8 fp = __builtin_bit_cast(bf16x8, uw);

      o0[j] = __builtin_amdgcn_mfma_f32_16x16x32_bf16(fp, av0, o0[j], 0, 0, 0);
      o1[j] = __builtin_amdgcn_mfma_f32_16x16x32_bf16(fp, av1, o1[j], 0, 0, 0);
      o2[j] = __builtin_amdgcn_mfma_f32_16x16x32_bf16(fp, am, o2[j], 0, 0, 0);
    }

    ak0 = nk0; ak1 = nk1; av0 = nv0; av1 = nv1; am = nm;
  }

#pragma unroll
  for (int j = 0; j < 4; ++j) {
#pragma unroll
    for (int r = 0; r < 4; ++r) {
      int ql = 16 * j + 4 * g + r;
      lo[wid][ql][c] = f2bf(o0[j][r]);
      lo[wid][ql][16 + c] = f2bf(o1[j][r]);
      if (c == 0) ll[wid][ql] = o2[j][r];
    }
  }
  __syncthreads();
  if (tid < 64) {
    float l = ll[0][tid] + ll[1][tid] + ll[2][tid] + ll[3][tid];
    linv[tid] = 1.f / l;
  }
  __syncthreads();

  for (int e = tid; e < 64 * 32; e += 256) {
    int q = e >> 5, d = e & 31;
    float s = bf2f(lo[0][q][d]) + bf2f(lo[1][q][d]) + bf2f(lo[2][q][d]) + bf2f(lo[3][q][d]);
    attnbf[(size_t)(b * S_ + q0 + q) * D_ + h * 32 + d] = f2bf(s * linv[q]);
  }
}

// ---- projection GEMM (green R16 verbatim) ----
__global__ __launch_bounds__(256) void proj_kernel(
    const ushort* __restrict__ attnbf,
    const ushort* __restrict__ wfrag,
    const float* __restrict__ bias,
    float* __restrict__ out) {
  __shared__ __align__(16) ushort sA[64][264];

  const int tid = threadIdx.x;
  const int wid = tid >> 6, lane = tid & 63;
  const int c = lane & 15, g = lane >> 4;
  const int mb0 = blockIdx.x * 64;
  const int m0 = mb0 + wid * 16;
  const int n0 = blockIdx.y * 64;

#pragma unroll
  for (int it = 0; it < 8; ++it) {
    int idx = tid + it * 256;
    int row = idx >> 5, c8 = idx & 31;
    uint4 v = *(const uint4*)(attnbf + (size_t)(mb0 + row) * D_ + c8 * 8);
    *(uint4*)(&sA[row][c8 * 8]) = v;
  }
  __syncthreads();

  f32x4 acc[4];
#pragma unroll
  for (int nb = 0; nb < 4; ++nb) acc[nb] = (f32x4){0.f, 0.f, 0.f, 0.f};

#pragma unroll
  for (int ks = 0; ks < 8; ++ks) {
    bf16x8 fa = load8(&sA[wid * 16 + c][ks * 32 + 8 * g]);
#pragma unroll
    for (int nb = 0; nb < 4; ++nb) {
      int nt = (n0 >> 4) + nb;
      bf16x8 fb = load8(wfrag + ((size_t)(nt * 8 + ks) * 64 + lane) * 8);
      acc[nb] = __builtin_amdgcn_mfma_f32_16x16x32_bf16(fa, fb, acc[nb], 0, 0, 0);
    }
  }

#pragma unroll
  for (int nb = 0; nb < 4; ++nb) {
    int n = n0 + nb * 16 + c;
    float bv = bias[n];
#pragma unroll
    for (int r = 0; r < 4; ++r) {
      int mrow = m0 + 4 * g + r;
      float v = acc[nb][r] + bv;
      out[(size_t)mrow * D_ + n] = fmaxf(v, 0.f);
    }
  }
}

extern "C" void kernel_launch(void* const* d_in, const int* in_sizes, int n_in,
                              void* d_out, int out_size, void* d_ws, size_t ws_size,
                              hipStream_t stream) {
  const float* x = (const float*)d_in[0];     // [B,S,D]
  const float* mask = (const float*)d_in[1];  // [B,S,1]
  const float* pos = (const float*)d_in[2];   // [B,S,D]
  const float* W = (const float*)d_in[3];     // [D,D]
  const float* bias = (const float*)d_in[4];  // [D]
  float* out = (float*)d_out;

  const size_t NE = (size_t)B_ * S_ * D_;  // 2097152
  // ws: posbf 4MB | frag 8MB | attnbf 4MB | wfrag 128KB | maskp 16KB
  ushort* posbf = (ushort*)d_ws;
  ushort* fragbuf = posbf + NE;                     // 4194304 elems
  ushort* attnbf = fragbuf + (size_t)4194304;
  ushort* wfragbuf = attnbf + NE;                   // D*D = 65536
  ushort* maskpbuf = wfragbuf + (size_t)D_ * D_;    // B*S = 8192

  prep_kernel<<<dim3(64, 33), 256, 0, stream>>>(x, mask, pos, W, posbf, fragbuf,
                                                maskpbuf, wfragbuf);
  attn_kernel<<<1024, 256, 0, stream>>>(posbf, fragbuf, maskpbuf, attnbf);
  proj_kernel<<<dim3((B_ * S_) / 64, D_ / 64), 256, 0, stream>>>(attnbf, wfragbuf, bias, out);
}

// Round 21
// 42.471 us; speedup vs baseline: 1.6867x; 1.0596x over previous
//
#include <hip/hip_runtime.h>
#include <hip/hip_bf16.h>
#include <math.h>

#define B_ 4
#define S_ 2048
#define D_ 256
#define H_ 8

typedef __attribute__((ext_vector_type(8))) __bf16 bf16x8;
typedef __attribute__((ext_vector_type(4))) float f32x4;

__device__ inline ushort f2bf(float x) {
  unsigned u = __builtin_bit_cast(unsigned, x);
  unsigned r = u + 0x7fffu + ((u >> 16) & 1u);
  return (ushort)(r >> 16);
}

__device__ inline float bf2f(ushort u) {
  unsigned v = ((unsigned)u) << 16;
  return __builtin_bit_cast(float, v);
}

__device__ inline unsigned cvtpk(float lo, float hi) {
  unsigned r;
  asm("v_cvt_pk_bf16_f32 %0, %1, %2" : "=v"(r) : "v"(lo), "v"(hi));
  return r;
}

__device__ inline bf16x8 load8(const ushort* p) {
  return __builtin_bit_cast(bf16x8, *(const uint4*)p);
}

// sqrt(RS * log2e), RS = 1/32^0.25 ; scores from scaled Q,K are C1*s directly,
// and the old fixed offset -16*log2e is a global 2^-23 factor that cancels in o/l.
#define SC_ 0.7788317f

// ---- unified prepass: grid (64, 33).
//  bh<32 : posbf (scaled pos -> bf16), frag K/V, maskp
//  bh==32: W fragment tile T (ks=T&7, np=T>>3) -> wfrag
__global__ __launch_bounds__(256) void prep_kernel(
    const float* __restrict__ x, const float* __restrict__ mask,
    const float* __restrict__ pos, const float* __restrict__ w,
    ushort* __restrict__ posbf, ushort* __restrict__ frag,
    ushort* __restrict__ maskp, ushort* __restrict__ wfrag) {
  __shared__ float Lx[32][33];
  __shared__ ushort Wt[32][33];
  const int T = blockIdx.x, bh = blockIdx.y;
  const int tid = threadIdx.x;

  if (bh == 32) {
    int ks = T & 7, np = T >> 3;
    int k0 = ks * 32, n0 = np * 32;
#pragma unroll
    for (int k = 0; k < 4; ++k) {
      int idx = tid + k * 256;  // 0..1023
      int ty = idx >> 5, tx = idx & 31;
      Wt[ty][tx] = f2bf(w[(k0 + ty) * D_ + n0 + tx]);
    }
    __syncthreads();
    if (tid < 128) {
      int sub = tid >> 6, lane = tid & 63;
      int c = lane & 15, g = lane >> 4;
      int nt = np * 2 + sub;
      ushort e[8];
#pragma unroll
      for (int i = 0; i < 8; ++i) e[i] = Wt[g * 8 + i][sub * 16 + c];
      uint4 fr;
      fr.x = (unsigned)e[0] | ((unsigned)e[1] << 16);
      fr.y = (unsigned)e[2] | ((unsigned)e[3] << 16);
      fr.z = (unsigned)e[4] | ((unsigned)e[5] << 16);
      fr.w = (unsigned)e[6] | ((unsigned)e[7] << 16);
      *(uint4*)(wfrag + ((size_t)(nt * 8 + ks) * 64 + lane) * 8) = fr;
    }
    return;
  }

  const int b = bh >> 3, h = bh & 7;
  const int slot = tid >> 6, lane = tid & 63;
  const int c = lane & 15, g = lane >> 4;
  const size_t rb = (size_t)(b * S_) + T * 32;  // global row base

  // (a) x * mask -> LDS f32 tile (float4 loads)
  {
    int row = tid >> 3, c4 = tid & 7;
    float mv = mask[rb + row];
    float4 v = *(const float4*)(x + (rb + row) * D_ + h * 32 + c4 * 4);
    Lx[row][c4 * 4 + 0] = v.x * mv;
    Lx[row][c4 * 4 + 1] = v.y * mv;
    Lx[row][c4 * 4 + 2] = v.z * mv;
    Lx[row][c4 * 4 + 3] = v.w * mv;
  }

  // (b) K slots: pos scaled by SC_ (folds the softmax scale into Q and K)
  if (slot < 2) {
    int row = slot * 16 + c;
    const float* ps = pos + (rb + row) * D_ + h * 32 + g * 8;
    float4 v0 = *(const float4*)ps;
    float4 v1 = *(const float4*)(ps + 4);
    uint4 fr;
    fr.x = (unsigned)f2bf(v0.x * SC_) | ((unsigned)f2bf(v0.y * SC_) << 16);
    fr.y = (unsigned)f2bf(v0.z * SC_) | ((unsigned)f2bf(v0.w * SC_) << 16);
    fr.z = (unsigned)f2bf(v1.x * SC_) | ((unsigned)f2bf(v1.y * SC_) << 16);
    fr.w = (unsigned)f2bf(v1.z * SC_) | ((unsigned)f2bf(v1.w * SC_) << 16);
    *(uint4*)(frag + ((size_t)(bh * 64 + T) * 4 + slot) * 512 + lane * 8) = fr;
    *(uint4*)(posbf + (rb + row) * D_ + h * 32 + g * 8) = fr;
  }

  __syncthreads();

  // (c) V slots
  if (slot >= 2) {
    int dcol = (slot - 2) * 16 + c;
    ushort e[8];
#pragma unroll
    for (int i = 0; i < 8; ++i) {
      int key = (i < 4) ? (4 * g + i) : (16 + 4 * g + (i - 4));  // kappa(g*8+i)
      e[i] = f2bf(Lx[key][dcol]);
    }
    uint4 fr;
    fr.x = (unsigned)e[0] | ((unsigned)e[1] << 16);
    fr.y = (unsigned)e[2] | ((unsigned)e[3] << 16);
    fr.z = (unsigned)e[4] | ((unsigned)e[5] << 16);
    fr.w = (unsigned)e[6] | ((unsigned)e[7] << 16);
    *(uint4*)(frag + ((size_t)(bh * 64 + T) * 4 + slot) * 512 + lane * 8) = fr;
  }

  // (d) kappa-permuted bf16 mask
  if (h == 0 && tid < 32) {
    int t = tid;
    int kx = ((t >> 1) & 12) + (t & 3) + ((t & 4) << 2);
    maskp[rb + t] = f2bf(mask[rb + kx]);
  }
}

// ---- flash attention (frozen green structure; p = exp2(s) directly) ----
__global__ __launch_bounds__(256, 3) void attn_kernel(
    const ushort* __restrict__ posbf,
    const ushort* __restrict__ frag,
    const ushort* __restrict__ maskp,
    ushort* __restrict__ attnbf) {
  __shared__ ushort lo[4][64][32];
  __shared__ float ll[4][64];
  __shared__ float linv[64];

  const int tid = threadIdx.x;
  const int wid = tid >> 6, lane = tid & 63;
  const int c = lane & 15, g = lane >> 4;
  const int blk = blockIdx.x;
  const int bh = blk & 31;
  const int qc = blk >> 5;
  const int b = bh >> 3, h = bh & 7;
  const int q0 = qc * 64;
  const int koff = wid * 512;

  const ushort* posb = posbf + (size_t)b * S_ * D_;

  bf16x8 fq[4];
#pragma unroll
  for (int j = 0; j < 4; ++j)
    fq[j] = load8(posb + (size_t)(q0 + 16 * j + c) * D_ + h * 32 + g * 8);

  const ushort* fragb = frag + ((size_t)bh * 64 + wid * 16) * 2048 + (size_t)lane * 8;
  const ushort* mb = maskp + (size_t)b * S_ + koff + g * 8;

  const f32x4 zero = {0.f, 0.f, 0.f, 0.f};
  f32x4 o0[4], o1[4], o2[4];
#pragma unroll
  for (int j = 0; j < 4; ++j) { o0[j] = zero; o1[j] = zero; o2[j] = zero; }

  bf16x8 ak0 = load8(fragb + 0 * 512);
  bf16x8 ak1 = load8(fragb + 1 * 512);
  bf16x8 av0 = load8(fragb + 2 * 512);
  bf16x8 av1 = load8(fragb + 3 * 512);
  bf16x8 am  = load8(mb);

  for (int t = 0; t < 16; ++t) {
    int tn = (t + 1) & 15;
    const ushort* fn = fragb + (size_t)tn * 2048;
    bf16x8 nk0 = load8(fn + 0 * 512);
    bf16x8 nk1 = load8(fn + 1 * 512);
    bf16x8 nv0 = load8(fn + 2 * 512);
    bf16x8 nv1 = load8(fn + 3 * 512);
    bf16x8 nm  = load8(mb + tn * 32);

#pragma unroll
    for (int j = 0; j < 4; ++j) {
      f32x4 s0 = __builtin_amdgcn_mfma_f32_16x16x32_bf16(ak0, fq[j], zero, 0, 0, 0);
      f32x4 s1 = __builtin_amdgcn_mfma_f32_16x16x32_bf16(ak1, fq[j], zero, 0, 0, 0);

      float p0 = __builtin_amdgcn_exp2f(s0[0]);
      float p1 = __builtin_amdgcn_exp2f(s0[1]);
      float p2 = __builtin_amdgcn_exp2f(s0[2]);
      float p3 = __builtin_amdgcn_exp2f(s0[3]);
      float p4 = __builtin_amdgcn_exp2f(s1[0]);
      float p5 = __builtin_amdgcn_exp2f(s1[1]);
      float p6 = __builtin_amdgcn_exp2f(s1[2]);
      float p7 = __builtin_amdgcn_exp2f(s1[3]);

      uint4 uw = make_uint4(cvtpk(p0, p1), cvtpk(p2, p3), cvtpk(p4, p5), cvtpk(p6, p7));
      bf16x8 fp = __builtin_bit_cast(bf16x8, uw);

      o0[j] = __builtin_amdgcn_mfma_f32_16x16x32_bf16(fp, av0, o0[j], 0, 0, 0);
      o1[j] = __builtin_amdgcn_mfma_f32_16x16x32_bf16(fp, av1, o1[j], 0, 0, 0);
      o2[j] = __builtin_amdgcn_mfma_f32_16x16x32_bf16(fp, am, o2[j], 0, 0, 0);
    }

    ak0 = nk0; ak1 = nk1; av0 = nv0; av1 = nv1; am = nm;
  }

#pragma unroll
  for (int j = 0; j < 4; ++j) {
#pragma unroll
    for (int r = 0; r < 4; ++r) {
      int ql = 16 * j + 4 * g + r;
      lo[wid][ql][c] = f2bf(o0[j][r]);
      lo[wid][ql][16 + c] = f2bf(o1[j][r]);
      if (c == 0) ll[wid][ql] = o2[j][r];
    }
  }
  __syncthreads();
  if (tid < 64) {
    float l = ll[0][tid] + ll[1][tid] + ll[2][tid] + ll[3][tid];
    linv[tid] = 1.f / l;
  }
  __syncthreads();

  for (int e = tid; e < 64 * 32; e += 256) {
    int q = e >> 5, d = e & 31;
    float s = bf2f(lo[0][q][d]) + bf2f(lo[1][q][d]) + bf2f(lo[2][q][d]) + bf2f(lo[3][q][d]);
    attnbf[(size_t)(b * S_ + q0 + q) * D_ + h * 32 + d] = f2bf(s * linv[q]);
  }
}

// ---- projection GEMM (green verbatim) ----
__global__ __launch_bounds__(256) void proj_kernel(
    const ushort* __restrict__ attnbf,
    const ushort* __restrict__ wfrag,
    const float* __restrict__ bias,
    float* __restrict__ out) {
  __shared__ __align__(16) ushort sA[64][264];

  const int tid = threadIdx.x;
  const int wid = tid >> 6, lane = tid & 63;
  const int c = lane & 15, g = lane >> 4;
  const int mb0 = blockIdx.x * 64;
  const int m0 = mb0 + wid * 16;
  const int n0 = blockIdx.y * 64;

#pragma unroll
  for (int it = 0; it < 8; ++it) {
    int idx = tid + it * 256;
    int row = idx >> 5, c8 = idx & 31;
    uint4 v = *(const uint4*)(attnbf + (size_t)(mb0 + row) * D_ + c8 * 8);
    *(uint4*)(&sA[row][c8 * 8]) = v;
  }
  __syncthreads();

  f32x4 acc[4];
#pragma unroll
  for (int nb = 0; nb < 4; ++nb) acc[nb] = (f32x4){0.f, 0.f, 0.f, 0.f};

#pragma unroll
  for (int ks = 0; ks < 8; ++ks) {
    bf16x8 fa = load8(&sA[wid * 16 + c][ks * 32 + 8 * g]);
#pragma unroll
    for (int nb = 0; nb < 4; ++nb) {
      int nt = (n0 >> 4) + nb;
      bf16x8 fb = load8(wfrag + ((size_t)(nt * 8 + ks) * 64 + lane) * 8);
      acc[nb] = __builtin_amdgcn_mfma_f32_16x16x32_bf16(fa, fb, acc[nb], 0, 0, 0);
    }
  }

#pragma unroll
  for (int nb = 0; nb < 4; ++nb) {
    int n = n0 + nb * 16 + c;
    float bv = bias[n];
#pragma unroll
    for (int r = 0; r < 4; ++r) {
      int mrow = m0 + 4 * g + r;
      float v = acc[nb][r] + bv;
      out[(size_t)mrow * D_ + n] = fmaxf(v, 0.f);
    }
  }
}

extern "C" void kernel_launch(void* const* d_in, const int* in_sizes, int n_in,
                              void* d_out, int out_size, void* d_ws, size_t ws_size,
                              hipStream_t stream) {
  const float* x = (const float*)d_in[0];     // [B,S,D]
  const float* mask = (const float*)d_in[1];  // [B,S,1]
  const float* pos = (const float*)d_in[2];   // [B,S,D]
  const float* W = (const float*)d_in[3];     // [D,D]
  const float* bias = (const float*)d_in[4];  // [D]
  float* out = (float*)d_out;

  const size_t NE = (size_t)B_ * S_ * D_;  // 2097152
  // ws: posbf 4MB | frag 8MB | attnbf 4MB | wfrag 128KB | maskp 16KB
  ushort* posbf = (ushort*)d_ws;
  ushort* fragbuf = posbf + NE;                     // 4194304 elems
  ushort* attnbf = fragbuf + (size_t)4194304;
  ushort* wfragbuf = attnbf + NE;                   // D*D = 65536
  ushort* maskpbuf = wfragbuf + (size_t)D_ * D_;    // B*S = 8192

  prep_kernel<<<dim3(64, 33), 256, 0, stream>>>(x, mask, pos, W, posbf, fragbuf,
                                                maskpbuf, wfragbuf);
  attn_kernel<<<1024, 256, 0, stream>>>(posbf, fragbuf, maskpbuf, attnbf);
  proj_kernel<<<dim3((B_ * S_) / 64, D_ / 64), 256, 0, stream>>>(attnbf, wfragbuf, bias, out);
}